// Round 2
// baseline (27.563 us; speedup 1.0000x reference)
//
#include <hip/hip_runtime.h>

// Capsule routing collapses algebraically:
//   c = softmax(b, axis=1)  =>  sum_m c[b,m,i] == 1 exactly
//   o = einsum('bmi,bnid->bnd', c, u_hat) = sum_i u_hat[b,n,i,d]
//   u_hat linear in u  =>  o[b,k] = sum_din (sum_i u[b,i,din]) * W[din,k]
// So: column-sum over I, then a tiny [32,512]x[512,512] GEMM.

constexpr int B    = 32;
constexpr int I    = 1024;
constexpr int DIN  = 512;
constexpr int K    = 512;            // NUM_CAPSULE * DIM_CAPSULE
constexpr int CHUNKS = 64;           // i-splits per batch (16 waves/CU occupancy)
constexpr int ROWS   = I / CHUNKS;   // 16 rows per chunk

// Kernel A: partial column sums of u over i.
// P[b][chunk][din] = sum_{r in chunk} u[b][chunk*ROWS + r][din]
// 128 threads/block, thread t owns dins 4t..4t+3 (float4, coalesced 2KB/iter).
// 2048 blocks = 8 blocks/CU = 16 waves/CU; 16 independent loads in flight.
__global__ __launch_bounds__(128) void colsum_kernel(
    const float* __restrict__ u, float* __restrict__ P) {
  const int b     = blockIdx.x >> 6;   // / CHUNKS
  const int chunk = blockIdx.x & 63;   // % CHUNKS
  const int t     = threadIdx.x;       // 0..127
  const float4* src = reinterpret_cast<const float4*>(
      u + ((size_t)b * I + (size_t)chunk * ROWS) * DIN) + t;
  float4 s = make_float4(0.f, 0.f, 0.f, 0.f);
  #pragma unroll
  for (int r = 0; r < ROWS; ++r) {
    float4 v = src[(size_t)r * (DIN / 4)];
    s.x += v.x; s.y += v.y; s.z += v.z; s.w += v.w;
  }
  reinterpret_cast<float4*>(P + ((size_t)b * CHUNKS + chunk) * DIN)[t] = s;
}

// Kernel B: U[b][din] = sum_c P[b][c][din]; out[b][k] = sum_din U[din]*W[din][k]
// grid = B * 8 blocks (8 k-tiles of 64), 256 threads = 4 din-groups x 64 k.
__global__ __launch_bounds__(256) void gemm_kernel(
    const float* __restrict__ P, const float* __restrict__ W,
    float* __restrict__ out) {
  const int b  = blockIdx.x >> 3;
  const int k0 = (blockIdx.x & 7) * 64;
  const int t  = threadIdx.x;

  __shared__ float U[DIN];
  __shared__ float red[4][64];

  // Stage 1: reduce partials into LDS (coalesced: 256 consecutive floats/iter).
  const float* Pb = P + (size_t)b * CHUNKS * DIN;
  float s0 = 0.f, s1 = 0.f;
  #pragma unroll 8
  for (int c = 0; c < CHUNKS; ++c) {
    s0 += Pb[(size_t)c * DIN + t];
    s1 += Pb[(size_t)c * DIN + t + 256];
  }
  U[t]       = s0;
  U[t + 256] = s1;
  __syncthreads();

  // Stage 2: GEMM slice. Wave = one din-group reading 64 consecutive W cols.
  const int kk = t & 63;
  const int dg = t >> 6;             // 0..3, din range [dg*128, dg*128+128)
  const float* Wp = W + (size_t)(dg * 128) * K + k0 + kk;
  float acc = 0.f;
  #pragma unroll 8
  for (int d = 0; d < 128; ++d)
    acc += U[dg * 128 + d] * Wp[(size_t)d * K];   // U read = wave broadcast
  red[dg][kk] = acc;
  __syncthreads();

  if (t < 64)
    out[(size_t)b * K + k0 + t] =
        red[0][t] + red[1][t] + red[2][t] + red[3][t];
}

extern "C" void kernel_launch(void* const* d_in, const int* in_sizes, int n_in,
                              void* d_out, int out_size, void* d_ws, size_t ws_size,
                              hipStream_t stream) {
  const float* u = (const float*)d_in[0];   // [32,1024,512] f32
  const float* W = (const float*)d_in[1];   // [1,512,512]   f32
  float* out = (float*)d_out;               // [32,32,16]    f32
  float* P   = (float*)d_ws;                // [32][64][512] f32 = 4 MiB

  colsum_kernel<<<B * CHUNKS, 128, 0, stream>>>(u, P);
  gemm_kernel<<<B * 8, 256, 0, stream>>>(P, W, out);
}

// Round 3
// 23.429 us; speedup vs baseline: 1.1765x; 1.1765x over previous
//
#include <hip/hip_runtime.h>

// Capsule routing collapses algebraically:
//   c = softmax(b, axis=1)  =>  sum_m c[b,m,i] == 1 exactly
//   o = einsum('bmi,bnid->bnd', c, u_hat) = sum_i u_hat[b,n,i,d]
//   u_hat linear in u  =>  o[b,k] = sum_din (sum_i u[b,i,din]) * W[din,k]
// So: column-sum over I, then a tiny [32,512]x[512,512] GEMM.

constexpr int B    = 32;
constexpr int I    = 1024;
constexpr int DIN  = 512;
constexpr int K    = 512;            // NUM_CAPSULE * DIM_CAPSULE
constexpr int CHUNKS = 32;           // i-splits per batch (round-1 best config)
constexpr int ROWS   = I / CHUNKS;   // 32 rows per chunk

// Kernel A: partial column sums of u over i (identical to round-1 best).
// P[b][chunk][din] = sum_{r in chunk} u[b][chunk*ROWS + r][din]
__global__ __launch_bounds__(128) void colsum_kernel(
    const float* __restrict__ u, float* __restrict__ P) {
  const int b     = blockIdx.x >> 5;   // / CHUNKS
  const int chunk = blockIdx.x & 31;   // % CHUNKS
  const int t     = threadIdx.x;       // 0..127
  const float4* src = reinterpret_cast<const float4*>(
      u + ((size_t)b * I + (size_t)chunk * ROWS) * DIN) + t;
  float4 s = make_float4(0.f, 0.f, 0.f, 0.f);
  #pragma unroll
  for (int r = 0; r < ROWS; ++r) {
    float4 v = src[(size_t)r * (DIN / 4)];
    s.x += v.x; s.y += v.y; s.z += v.z; s.w += v.w;
  }
  reinterpret_cast<float4*>(P + ((size_t)b * CHUNKS + chunk) * DIN)[t] = s;
}

// Kernel B (lean): U[b] = sum_c P[b][c]; out[b][k] = sum_d U[d]*W[d][k]
// grid = B*8 blocks (64-wide k-tiles), 256 threads.
// Stage 1 vectorized: thread t sums 16 float4s of its half of the chunks.
__global__ __launch_bounds__(256) void gemm_kernel(
    const float* __restrict__ P, const float* __restrict__ W,
    float* __restrict__ out) {
  const int b  = blockIdx.x >> 3;
  const int k0 = (blockIdx.x & 7) * 64;
  const int t  = threadIdx.x;

  __shared__ float  U[DIN];
  __shared__ float4 Uh[2][DIN / 4];
  __shared__ float  red[4][64];

  // Stage 1: P[b] viewed as [CHUNKS][128] float4. col = t&127, half = t>>7.
  const float4* P4 = reinterpret_cast<const float4*>(P + (size_t)b * CHUNKS * DIN);
  const int col = t & 127, half = t >> 7;
  float4 s = make_float4(0.f, 0.f, 0.f, 0.f);
  #pragma unroll
  for (int c = 0; c < CHUNKS / 2; ++c) {
    float4 v = P4[(size_t)(half * (CHUNKS / 2) + c) * (DIN / 4) + col];
    s.x += v.x; s.y += v.y; s.z += v.z; s.w += v.w;
  }
  Uh[half][col] = s;
  __syncthreads();
  if (t < DIN / 4) {
    float4 a = Uh[0][t], c4 = Uh[1][t];
    U[4 * t + 0] = a.x + c4.x;
    U[4 * t + 1] = a.y + c4.y;
    U[4 * t + 2] = a.z + c4.z;
    U[4 * t + 3] = a.w + c4.w;
  }
  __syncthreads();

  // Stage 2: wave = one din-group of 128, 64 consecutive W cols; deep unroll
  // so ~16 independent L2 loads stay in flight.
  const int kk = t & 63;
  const int dg = t >> 6;
  const float* Wp = W + (size_t)(dg * 128) * K + k0 + kk;
  float acc = 0.f;
  #pragma unroll 16
  for (int d = 0; d < 128; ++d)
    acc += U[dg * 128 + d] * Wp[(size_t)d * K];   // U read = wave broadcast
  red[dg][kk] = acc;
  __syncthreads();

  if (t < 64)
    out[(size_t)b * K + k0 + t] =
        red[0][t] + red[1][t] + red[2][t] + red[3][t];
}

extern "C" void kernel_launch(void* const* d_in, const int* in_sizes, int n_in,
                              void* d_out, int out_size, void* d_ws, size_t ws_size,
                              hipStream_t stream) {
  const float* u = (const float*)d_in[0];   // [32,1024,512] f32
  const float* W = (const float*)d_in[1];   // [1,512,512]   f32
  float* out = (float*)d_out;               // [32,32,16]    f32
  float* P   = (float*)d_ws;                // [32][32][512] f32 = 2 MiB

  colsum_kernel<<<B * CHUNKS, 128, 0, stream>>>(u, P);
  gemm_kernel<<<B * 8, 256, 0, stream>>>(P, W, out);
}